// Round 9
// baseline (247.914 us; speedup 1.0000x reference)
//
#include <hip/hip_runtime.h>

constexpr int FRAME_LEN = 130;   // floats per frame
constexpr int HALF      = 65;    // floats per hand block
constexpr int BLOCK     = 256;   // threads per block
constexpr int FPB       = 32;    // frames per chunk
constexpr int CHUNK_F   = FPB * FRAME_LEN;   // 4160 floats
constexpr int CHUNK_F2  = CHUNK_F / 2;       // 2080 float2 = 8*256 + 32
constexpr int MAXGRID   = 1024;              // 4 blocks/CU * 256 CU: fully resident

typedef float v4f __attribute__((ext_vector_type(4), aligned(4)));

// frame = idx / 130 for idx < 7825 via magic multiply
__device__ __forceinline__ int div130(int idx) {
    return (int)(((unsigned)idx * 8067u) >> 20);
}

__device__ __forceinline__ bool skip_pred(float h0, float p0, float h1, float p1) {
    const bool nan0 = (h0 != h0);
    const bool nan1 = (h1 != h1);
    const bool no_nan = !nan0 && !nan1;
    const bool eq = (h0 == h1);
    return (h1 > h0) ||
           (nan0 && nan1) ||
           (nan0 && (h1 == 1.0f)) ||
           (nan1 && (h0 == 0.0f)) ||
           (no_nan && eq && (h0 == 0.0f) && (p0 > p1)) ||
           (no_nan && eq && (h0 == 1.0f) && (p0 < p1));
}

// Header prefetch for chunk cid: lanes (all 64; lane&31 selects frame) load
// [h0 p0 . .] and [. h1 p1 .].  Issued one pipeline stage ahead.
__device__ __forceinline__ void issue_hdr(const float* __restrict__ X, long long cid,
                                          int lane, v4f& ha, v4f& hb) {
    const float* fr = X + cid * CHUNK_F + (lane & 31) * FRAME_LEN;
    ha = *(const v4f*)fr;
    hb = *(const v4f*)(fr + 64);
}

// Gather-on-load: 9 float2 per thread per chunk, branchless (R5-proven math).
// The permutation is applied in the load addresses; store phase is pure stores.
__device__ __forceinline__ void load_chunk(const float* __restrict__ Xb,
                                           unsigned mask, int t, float2 (&r)[9]) {
#pragma unroll
    for (int k = 0; k < 9; ++k) {
        const int g = (k < 8) ? (t + k * 256) : ((t & 31) + 2048); // tail clamped
        const int idx = 2 * g;
        const int fl  = div130(idx);
        const int jj  = idx - fl * FRAME_LEN;
        const bool sk = (mask >> fl) & 1u;
        const int d0  = sk ? 0 : (jj     < HALF ? HALF : -HALF);
        const int d1  = sk ? 0 : (jj + 1 < HALF ? HALF : -HALF);
        const int fb  = fl * FRAME_LEN;
        r[k].x = Xb[fb + jj     + d0];
        r[k].y = Xb[fb + jj + 1 + d1];
    }
}

// Keep the whole batch live so the compiler cannot sink loads to save regs
// (R7-proven: without this it re-serializes; with it, VGPR hits the cap).
__device__ __forceinline__ void pin9(float2 (&r)[9]) {
    asm volatile("" : "+v"(r[0]), "+v"(r[1]), "+v"(r[2]), "+v"(r[3]), "+v"(r[4]),
                      "+v"(r[5]), "+v"(r[6]), "+v"(r[7]), "+v"(r[8]));
}

__device__ __forceinline__ void store_chunk(float* __restrict__ Ob, int t,
                                            float2 (&r)[9]) {
    float2* __restrict__ Ov = (float2*)Ob;
#pragma unroll
    for (int k = 0; k < 8; ++k) Ov[t + k * 256] = r[k];
    if (t < CHUNK_F2 - 2048) Ov[t + 2048] = r[8];
}

// One pipeline step: process chunk c from set CUR; prefetch chunk c+G into NXT.
// Invariant on entry: r[CUR]=data(c) in flight; hd[NXT]=headers(c+G) in flight.
// Issue order hdr-before-data keeps all vmcnt waits counted (never a full drain).
template <int CUR, int NXT>
__device__ __forceinline__ bool pipe_step(const float* __restrict__ X,
        float* __restrict__ out, long long& c, long long G, long long full,
        int t, int lane, float2 (&r)[2][9], unsigned (&msk)[2], v4f (&hd)[2][2]) {
    const long long cn = c + G;
    const bool more = (cn < full);
    if (more) {
        const long long cnn = cn + G;
        if (cnn < full)                         // issue next headers FIRST
            issue_hdr(X, cnn, lane, hd[CUR][0], hd[CUR][1]);
        msk[NXT] = (unsigned)__ballot(
            skip_pred(hd[NXT][0].x, hd[NXT][0].y, hd[NXT][1].y, hd[NXT][1].z));
        load_chunk(X + cn * CHUNK_F, msk[NXT], t, r[NXT]);
        pin9(r[NXT]);
    }
    store_chunk(out + c * CHUNK_F, t, r[CUR]);
    c = cn;
    return !more;
}

__global__ __launch_bounds__(BLOCK, 4)
void hand_sorter_kernel(const float* __restrict__ X, float* __restrict__ out,
                        int n_frames) {
    const int t = threadIdx.x;
    const int lane = t & 63;
    const long long full = n_frames / FPB;       // full 32-frame chunks
    const long long G = gridDim.x;
    long long c = blockIdx.x;

    if (c < full) {
        float2 r[2][9];
        unsigned msk[2];
        v4f hd[2][2];

        // ---- prologue: mask(c) serially, then establish the pipeline ----
        issue_hdr(X, c, lane, hd[0][0], hd[0][1]);
        msk[0] = (unsigned)__ballot(
            skip_pred(hd[0][0].x, hd[0][0].y, hd[0][1].y, hd[0][1].z));
        if (c + G < full)                        // headers one stage ahead
            issue_hdr(X, c + G, lane, hd[1][0], hd[1][1]);
        load_chunk(X + c * CHUNK_F, msk[0], t, r[0]);
        pin9(r[0]);

        // ---- steady state: alternate register sets, template-constant idx ----
        while (true) {
            if (pipe_step<0, 1>(X, out, c, G, full, t, lane, r, msk, hd)) break;
            if (pipe_step<1, 0>(X, out, c, G, full, t, lane, r, msk, hd)) break;
        }
    }

    // ---- remainder frames (n_frames % FPB) — block 0, scalar path ----
    if (blockIdx.x == 0) {
        const int nrem = n_frames - (int)(full * FPB);
        if (nrem > 0) {
            const long long base = full * (long long)CHUNK_F;
            const float* __restrict__ Xb = X + base;
            float* __restrict__ Ob = out + base;
            const int nf = nrem * FRAME_LEN;
            for (int i = t; i < nf; i += BLOCK) {
                const int fle = div130(i);
                const int je  = i - fle * FRAME_LEN;
                const float* fr = Xb + fle * FRAME_LEN;
                const bool sk = skip_pred(fr[0], fr[1], fr[HALF], fr[HALF + 1]);
                const int sj = je + (sk ? 0 : (je < HALF ? HALF : -HALF));
                Ob[i] = fr[sj];
            }
        }
    }
}

extern "C" void kernel_launch(void* const* d_in, const int* in_sizes, int n_in,
                              void* d_out, int out_size, void* d_ws, size_t ws_size,
                              hipStream_t stream) {
    const float* X = (const float*)d_in[0];
    float* out = (float*)d_out;
    const int n_frames = in_sizes[0] / FRAME_LEN;   // 262144
    const long long full = n_frames / FPB;           // 8192 chunks
    int n_blocks = (int)(full < MAXGRID ? (full > 0 ? full : 1) : MAXGRID);
    hand_sorter_kernel<<<n_blocks, BLOCK, 0, stream>>>(X, out, n_frames);
}